// Round 3
// baseline (318.971 us; speedup 1.0000x reference)
//
#include <hip/hip_runtime.h>
#include <math.h>

#define ACC_BITS 23

typedef float f32x4 __attribute__((ext_vector_type(4)));

#define TPB   256
#define VPT   4                      // float4 vectors per thread
#define TILE  (TPB * VPT)            // 1024 float4 per block-tile
#define NBLK  1024                   // persistent: 4 blocks/CU, all co-resident

// Fixed-point requant parameters, computed in-register per thread (uniform).
struct QP {
    float scale;
    int   fast;                       // 1 => 24-bit fast path valid
    int   nmx_hi, nmx_lo, Kx, srx12;  // x:  nm split 12/12, K=2^(sr-1), sr-12
    int   nmi_hi, nmi_lo, Ki, sri12;  // id: same
    long long nm_x64, nm_i64;         // generic fallback
    int   e_x, e_i;
};

// Bit-exact vs reference: fp32 scale divide, fp64 ns, frexp, round-half-even
// mantissa quantization (rint == jnp.round). Runs under the prologue loads.
__device__ __forceinline__ QP compute_qparams(float pre, float idsf,
                                              float xmn, float xmx) {
    QP q;
    float s     = fmaxf(fmaxf(fabsf(xmn), fabsf(xmx)), 1e-8f);
    float scale = s / 127.0f;

    double s64  = (double)scale;
    double ns_x = (double)pre  / s64;
    double ns_i = (double)idsf / s64;

    int e_x, e_i;
    double m_x = frexp(ns_x, &e_x);           // m in [0.5,1)
    double m_i = frexp(ns_i, &e_i);
    long long nm_x = (long long)rint(m_x * 8388608.0);   // round-half-even
    long long nm_i = (long long)rint(m_i * 8388608.0);

    q.scale  = scale;
    q.nm_x64 = nm_x;  q.e_x = e_x;
    q.nm_i64 = nm_i;  q.e_i = e_i;

    // Normalize nm == 2^23 -> (2^22, e+1). Result-identical (R3 note, prior
    // session: the rounded numerator is always even in that case).
    long long ax = nm_x, ai = nm_i;
    int ex = e_x, ei = e_i;
    if (ax == (1LL << 23)) { ax >>= 1; ex += 1; }
    if (ai == (1LL << 23)) { ai >>= 1; ei += 1; }
    int sr_x = ACC_BITS - ex, sr_i = ACC_BITS - ei;

    q.fast = (ax > 0) && (ax < (1LL << 23)) &&
             (ai > 0) && (ai < (1LL << 23)) &&
             (sr_x >= 12) && (sr_x <= 30) && (sr_i >= 12) && (sr_i <= 30);
    q.nmx_hi = (int)(ax >> 12); q.nmx_lo = (int)(ax & 0xFFF);
    q.nmi_hi = (int)(ai >> 12); q.nmi_lo = (int)(ai & 0xFFF);
    q.Kx = q.fast ? (1 << (sr_x - 1)) : 0;
    q.Ki = q.fast ? (1 << (sr_i - 1)) : 0;
    q.srx12 = sr_x - 12;
    q.sri12 = sr_i - 12;
    return q;
}

// Generic bit-exact replica (fallback + partial tiles + scalar tail).
__device__ __forceinline__ long long fixed_point_mul64(long long xi, long long nm, int e) {
    long long tmp = xi * nm;
    if (e - ACC_BITS >= 0) {
        return tmp << (e - ACC_BITS);
    } else {
        int sr = ACC_BITS - e;
        long long nudge = (1LL << (sr - 1)) - (long long)(tmp < 0);
        return (tmp + nudge) >> sr;
    }
}

// Full-rate 24-bit-multiply fixed-point mul (bit-exact for |xi|<2^19,
// 0<nm<2^23, 12<=sr<=30; R3 derivation from prior session).
__device__ __forceinline__ int fpm24(int xi, int nm_hi, int nm_lo, int K, int sr12) {
    int bit = (int)((unsigned)xi >> 31);
    int B = (__mul24(xi, nm_lo) + K - bit) >> 12;
    int A = __mul24(xi, nm_hi);
    return (A + B) >> sr12;
}

// Issue the 8 loads of one tile, pairwise x/id interleaved.
__device__ __forceinline__ void load_tile(const f32x4* __restrict__ x,
                                          const f32x4* __restrict__ idn,
                                          int tl, int tid, int n4,
                                          f32x4 (&xv)[VPT], f32x4 (&iv)[VPT]) {
    const int b = tl * TILE + tid;
    if (b + (VPT - 1) * TPB < n4) {
        #pragma unroll
        for (int k = 0; k < VPT; ++k) {
            xv[k] = x  [b + k * TPB];
            iv[k] = idn[b + k * TPB];
        }
    } else {
        #pragma unroll
        for (int k = 0; k < VPT; ++k) {
            int i = b + k * TPB;
            if (i < n4) { xv[k] = x[i]; iv[k] = idn[i]; }
            else        { xv[k] = (f32x4)0.f; iv[k] = (f32x4)0.f; }
        }
    }
}

// Compute + store one tile from a register buffer.
__device__ __forceinline__ void process_tile(const f32x4 (&xv)[VPT],
                                             const f32x4 (&iv)[VPT],
                                             f32x4* __restrict__ out,
                                             int tl, int tid, int n4,
                                             const QP& q) {
    const int b = tl * TILE + tid;
    const float scale = q.scale;
    if (q.fast && (b + (VPT - 1) * TPB < n4)) {
        #pragma unroll
        for (int k = 0; k < VPT; ++k) {
            f32x4 ov;
            #pragma unroll
            for (int c = 0; c < 4; ++c) {
                int o = fpm24((int)xv[k][c], q.nmx_hi, q.nmx_lo, q.Kx, q.srx12)
                      + fpm24((int)iv[k][c], q.nmi_hi, q.nmi_lo, q.Ki, q.sri12);
                o = o < -128 ? -128 : (o > 127 ? 127 : o);   // v_med3_i32
                ov[c] = (float)o * scale;
            }
            out[b + k * TPB] = ov;
        }
    } else {
        // Rare: generic-math (always bit-exact) + guarded stores.
        #pragma unroll
        for (int k = 0; k < VPT; ++k) {
            int i = b + k * TPB;
            if (i < n4) {
                f32x4 ov;
                #pragma unroll
                for (int c = 0; c < 4; ++c) {
                    long long o = fixed_point_mul64((long long)xv[k][c], q.nm_x64, q.e_x)
                                + fixed_point_mul64((long long)iv[k][c], q.nm_i64, q.e_i);
                    o = o < -128 ? -128 : (o > 127 ? 127 : o);
                    ov[c] = (float)(int)o * scale;
                }
                out[i] = ov;
            }
        }
    }
}

// Persistent double-buffered streaming kernel.
// R2 post-mortem: one-shot blocks sawtooth (load burst -> drain -> compute ->
// store -> exit -> relaunch gap); chip-wide outstanding reads collapse
// between bursts (occupancy 62-72% on a 36-VGPR LDS-free kernel is the
// tell). Here 1024 blocks (4/CU) stay resident the whole kernel; while
// tile t is computed/stored from buffer A, tile t+NBLK's 8 loads are in
// flight into buffer B — the compiler emits the counted-vmcnt wait for A
// only, so HBM sees a continuous request stream.
__global__ void __launch_bounds__(TPB, 4)
quantact_fused(const f32x4* __restrict__ x,
               const f32x4* __restrict__ idn,
               f32x4* __restrict__ out,
               float* __restrict__ out_scale,
               const float* __restrict__ pre_sf,
               const float* __restrict__ id_sf,
               const float* __restrict__ xminp,
               const float* __restrict__ xmaxp,
               int n4, int n)
{
    const int tid    = (int)threadIdx.x;
    const int ntiles = (n4 + TILE - 1) / TILE;
    const int nb     = (int)gridDim.x;

    // Uniform scalar param loads (s_load) — issue first.
    const float pre  = pre_sf[0];
    const float idsf = id_sf[0];
    const float xmn  = xminp[0];
    const float xmx  = xmaxp[0];

    int t = (int)blockIdx.x;
    f32x4 xa[VPT], ia[VPT], xb[VPT], ib[VPT];

    if (t < ntiles) load_tile(x, idn, t, tid, n4, xa, ia);
    __builtin_amdgcn_sched_barrier(0);      // prologue loads in flight first

    const QP q = compute_qparams(pre, idsf, xmn, xmx);
    if (blockIdx.x == 0 && tid == 0) *out_scale = q.scale;  // tuple output 1

    if (t < ntiles) {
        for (;;) {
            int t2 = t + nb;
            if (t2 >= ntiles) { process_tile(xa, ia, out, t, tid, n4, q); break; }
            load_tile(x, idn, t2, tid, n4, xb, ib);          // prefetch into B
            __builtin_amdgcn_sched_barrier(0);
            process_tile(xa, ia, out, t, tid, n4, q);        // waits A only
            t = t2;

            int t3 = t + nb;
            if (t3 >= ntiles) { process_tile(xb, ib, out, t, tid, n4, q); break; }
            load_tile(x, idn, t3, tid, n4, xa, ia);          // prefetch into A
            __builtin_amdgcn_sched_barrier(0);
            process_tile(xb, ib, out, t, tid, n4, q);        // waits B only
            t = t3;
        }
    }

    // scalar tail for n % 4 != 0 (not hit at this shape)
    if (blockIdx.x == 0) {
        const float* xs  = (const float*)x;
        const float* is_ = (const float*)idn;
        float* os = (float*)out;
        for (int j = n4 * 4 + tid; j < n; j += TPB) {
            long long o = fixed_point_mul64((long long)xs[j], q.nm_x64, q.e_x)
                        + fixed_point_mul64((long long)is_[j], q.nm_i64, q.e_i);
            o = o < -128 ? -128 : (o > 127 ? 127 : o);
            os[j] = (float)(int)o * q.scale;
        }
    }
}

extern "C" void kernel_launch(void* const* d_in, const int* in_sizes, int n_in,
                              void* d_out, int out_size, void* d_ws, size_t ws_size,
                              hipStream_t stream) {
    const f32x4* x      = (const f32x4*)d_in[0];
    const f32x4* idn    = (const f32x4*)d_in[1];
    const float* pre_sf = (const float*)d_in[2];
    const float* id_sf  = (const float*)d_in[3];
    const float* xmin   = (const float*)d_in[4];
    const float* xmax   = (const float*)d_in[5];

    int n  = in_sizes[0];          // 33,554,432
    int n4 = n / 4;                // 8,388,608 float4

    float* out       = (float*)d_out;
    float* out_scale = out + n;    // tuple output 1 (flat-concatenated)

    int ntiles = (n4 + TILE - 1) / TILE;    // 8192 at this shape
    int grid   = ntiles < NBLK ? (ntiles < 1 ? 1 : ntiles) : NBLK;
    quantact_fused<<<grid, TPB, 0, stream>>>(x, idn, (f32x4*)out, out_scale,
                                             pre_sf, id_sf, xmin, xmax, n4, n);
}

// Round 4
// 298.470 us; speedup vs baseline: 1.0687x; 1.0687x over previous
//
#include <hip/hip_runtime.h>
#include <math.h>

#define ACC_BITS 23

typedef float f32x4 __attribute__((ext_vector_type(4)));

#define TPB   256
#define VPT   4                      // float4 vectors per thread
#define TILE  (TPB * VPT)            // 1024 float4 per block

// Fixed-point requant parameters, computed in-register per thread (uniform).
struct QP {
    float scale;
    int   fast;                       // 1 => 24-bit fast path valid
    int   nmx_hi, nmx_lo, Kx, srx12;  // x:  nm split 12/12, K=2^(sr-1), sr-12
    int   nmi_hi, nmi_lo, Ki, sri12;  // id: same
    long long nm_x64, nm_i64;         // generic fallback
    int   e_x, e_i;
};

// Bit-exact vs reference: fp32 scale divide, fp64 ns, frexp, round-half-even
// mantissa quantization (rint == jnp.round). Runs under the 8 in-flight loads.
__device__ __forceinline__ QP compute_qparams(float pre, float idsf,
                                              float xmn, float xmx) {
    QP q;
    float s     = fmaxf(fmaxf(fabsf(xmn), fabsf(xmx)), 1e-8f);
    float scale = s / 127.0f;

    double s64  = (double)scale;
    double ns_x = (double)pre  / s64;
    double ns_i = (double)idsf / s64;

    int e_x, e_i;
    double m_x = frexp(ns_x, &e_x);           // m in [0.5,1)
    double m_i = frexp(ns_i, &e_i);
    long long nm_x = (long long)rint(m_x * 8388608.0);   // round-half-even
    long long nm_i = (long long)rint(m_i * 8388608.0);

    q.scale  = scale;
    q.nm_x64 = nm_x;  q.e_x = e_x;
    q.nm_i64 = nm_i;  q.e_i = e_i;

    // Normalize nm == 2^23 -> (2^22, e+1). Result-identical (R3 note, prior
    // session: the rounded numerator is always even in that case).
    long long ax = nm_x, ai = nm_i;
    int ex = e_x, ei = e_i;
    if (ax == (1LL << 23)) { ax >>= 1; ex += 1; }
    if (ai == (1LL << 23)) { ai >>= 1; ei += 1; }
    int sr_x = ACC_BITS - ex, sr_i = ACC_BITS - ei;

    q.fast = (ax > 0) && (ax < (1LL << 23)) &&
             (ai > 0) && (ai < (1LL << 23)) &&
             (sr_x >= 12) && (sr_x <= 30) && (sr_i >= 12) && (sr_i <= 30);
    q.nmx_hi = (int)(ax >> 12); q.nmx_lo = (int)(ax & 0xFFF);
    q.nmi_hi = (int)(ai >> 12); q.nmi_lo = (int)(ai & 0xFFF);
    q.Kx = q.fast ? (1 << (sr_x - 1)) : 0;
    q.Ki = q.fast ? (1 << (sr_i - 1)) : 0;
    q.srx12 = sr_x - 12;
    q.sri12 = sr_i - 12;
    return q;
}

// Generic bit-exact replica (fallback + tail).
__device__ __forceinline__ long long fixed_point_mul64(long long xi, long long nm, int e) {
    long long tmp = xi * nm;
    if (e - ACC_BITS >= 0) {
        return tmp << (e - ACC_BITS);
    } else {
        int sr = ACC_BITS - e;
        long long nudge = (1LL << (sr - 1)) - (long long)(tmp < 0);
        return (tmp + nudge) >> sr;
    }
}

// Full-rate 24-bit-multiply fixed-point mul (bit-exact for |xi|<2^19,
// 0<nm<2^23, 12<=sr<=30; R3 derivation from prior session).
__device__ __forceinline__ int fpm24(int xi, int nm_hi, int nm_lo, int K, int sr12) {
    int bit = (int)((unsigned)xi >> 31);
    int B = (__mul24(xi, nm_lo) + K - bit) >> 12;
    int A = __mul24(xi, nm_hi);
    return (A + B) >> sr12;
}

// R2 structure (best measured: 112 us) + NONTEMPORAL LOADS on both inputs.
// Experiment: FETCH_SIZE == exactly one input's worth (134 MB) every round.
// Either (a) ~50% of input reads really hit L2/L3 (cyclic thrash of a 402 MB
// working set through 256 MB L3) and the hit/alloc/victim path is what caps
// delivered BW at 3.6 TB/s, or (b) the counter undercounts reads 2x and
// there are no hits. nt loads (no-allocate) discriminate: (a) -> FETCH
// doubles AND dur drops; fabric-cap -> FETCH doubles, dur flat; artifact ->
// FETCH unchanged. Stores stay cached (R1: nt stores cost +13 us).
__global__ void __launch_bounds__(TPB)
quantact_fused(const f32x4* __restrict__ x,
               const f32x4* __restrict__ idn,
               f32x4* __restrict__ out,
               float* __restrict__ out_scale,
               const float* __restrict__ pre_sf,
               const float* __restrict__ id_sf,
               const float* __restrict__ xminp,
               const float* __restrict__ xmaxp,
               int n4, int n)
{
    const int base = blockIdx.x * TILE + (int)threadIdx.x;
    const bool full = (base + (VPT - 1) * TPB) < n4;

    // Uniform scalar loads (s_load, lgkmcnt) — issue first.
    const float pre  = pre_sf[0];
    const float idsf = id_sf[0];
    const float xmn  = xminp[0];
    const float xmx  = xmaxp[0];

    // All 8 vector loads, pairwise interleaved, nontemporal (no-allocate).
    f32x4 xv[VPT], iv[VPT];
    if (full) {
        #pragma unroll
        for (int k = 0; k < VPT; ++k) {
            xv[k] = __builtin_nontemporal_load(&x[base + k * TPB]);
            iv[k] = __builtin_nontemporal_load(&idn[base + k * TPB]);
        }
    }
    // Nothing may hoist above; no load may sink below.
    __builtin_amdgcn_sched_barrier(0);

    const QP q = compute_qparams(pre, idsf, xmn, xmx);
    const float scale = q.scale;

    if (blockIdx.x == 0 && threadIdx.x == 0) *out_scale = scale;  // tuple out 1

    if (q.fast) {
        const int nmx_hi = q.nmx_hi, nmx_lo = q.nmx_lo, Kx = q.Kx, srx = q.srx12;
        const int nmi_hi = q.nmi_hi, nmi_lo = q.nmi_lo, Ki = q.Ki, sri = q.sri12;

        if (full) {
            #pragma unroll
            for (int k = 0; k < VPT; ++k) {
                f32x4 ov;
                #pragma unroll
                for (int c = 0; c < 4; ++c) {
                    int o = fpm24((int)xv[k][c], nmx_hi, nmx_lo, Kx, srx)
                          + fpm24((int)iv[k][c], nmi_hi, nmi_lo, Ki, sri);
                    o = o < -128 ? -128 : (o > 127 ? 127 : o);   // v_med3_i32
                    ov[c] = (float)o * scale;
                }
                out[base + k * TPB] = ov;
            }
        } else {
            #pragma unroll
            for (int k = 0; k < VPT; ++k) {
                int i = base + k * TPB;
                if (i < n4) {
                    f32x4 xw = x[i], iw = idn[i], ov;
                    #pragma unroll
                    for (int c = 0; c < 4; ++c) {
                        int o = fpm24((int)xw[c], nmx_hi, nmx_lo, Kx, srx)
                              + fpm24((int)iw[c], nmi_hi, nmi_lo, Ki, sri);
                        o = o < -128 ? -128 : (o > 127 ? 127 : o);
                        ov[c] = (float)o * scale;
                    }
                    out[i] = ov;
                }
            }
        }
    } else {
        // Generic path: exact 64-bit replica of the reference branches.
        const long long nm64_x = q.nm_x64, nm64_i = q.nm_i64;
        const int e_x = q.e_x, e_i = q.e_i;
        #pragma unroll
        for (int k = 0; k < VPT; ++k) {
            int i = base + k * TPB;
            if (i < n4) {
                f32x4 xw, iw, ov;
                if (full) { xw = xv[k]; iw = iv[k]; }
                else      { xw = x[i];  iw = idn[i]; }
                #pragma unroll
                for (int c = 0; c < 4; ++c) {
                    long long o = fixed_point_mul64((long long)xw[c], nm64_x, e_x)
                                + fixed_point_mul64((long long)iw[c], nm64_i, e_i);
                    o = o < -128 ? -128 : (o > 127 ? 127 : o);
                    ov[c] = (float)(int)o * scale;
                }
                out[i] = ov;
            }
        }
    }

    // scalar tail for n % 4 != 0 (not hit at this shape)
    if (blockIdx.x == 0) {
        const float* xs  = (const float*)x;
        const float* is_ = (const float*)idn;
        float* os = (float*)out;
        const long long nm64_x = q.nm_x64, nm64_i = q.nm_i64;
        const int e_x = q.e_x, e_i = q.e_i;
        for (int j = n4 * 4 + (int)threadIdx.x; j < n; j += TPB) {
            long long o = fixed_point_mul64((long long)xs[j], nm64_x, e_x)
                        + fixed_point_mul64((long long)is_[j], nm64_i, e_i);
            o = o < -128 ? -128 : (o > 127 ? 127 : o);
            os[j] = (float)(int)o * scale;
        }
    }
}

extern "C" void kernel_launch(void* const* d_in, const int* in_sizes, int n_in,
                              void* d_out, int out_size, void* d_ws, size_t ws_size,
                              hipStream_t stream) {
    const f32x4* x      = (const f32x4*)d_in[0];
    const f32x4* idn    = (const f32x4*)d_in[1];
    const float* pre_sf = (const float*)d_in[2];
    const float* id_sf  = (const float*)d_in[3];
    const float* xmin   = (const float*)d_in[4];
    const float* xmax   = (const float*)d_in[5];

    int n  = in_sizes[0];          // 33,554,432
    int n4 = n / 4;                // 8,388,608 float4

    float* out       = (float*)d_out;
    float* out_scale = out + n;    // tuple output 1 (flat-concatenated)

    int grid = (n4 + TILE - 1) / TILE;   // 8192 blocks, one-shot
    if (grid < 1) grid = 1;
    quantact_fused<<<grid, TPB, 0, stream>>>(x, idn, (f32x4*)out, out_scale,
                                             pre_sf, id_sf, xmin, xmax, n4, n);
}